// Round 3
// 988.933 us; speedup vs baseline: 1.2127x; 1.2127x over previous
//
#include <hip/hip_runtime.h>

#define NSEG 128
#define BB 2
#define CC 768
#define CC2 (CC/2)          // 384 channel pairs
#define HP 28
#define WP 28
#define HI 392
#define WI 392
#define NPIX (HI*WI)        // 153664
#define NPIX4 (NPIX/4)      // 38416
#define CPB2 32             // channel-pairs per paint block (64 channels, 32 KB table slice)

typedef float f32x4 __attribute__((ext_vector_type(4)));   // native vector for nontemporal store

// Pack clamped segment ids to uint8, 4 pixels/thread.
__global__ void pid_kernel(const int* __restrict__ mask, unsigned int* __restrict__ sb) {
    int g = blockIdx.x * blockDim.x + threadIdx.x;
    if (g >= BB * NPIX4) return;
    int4 m = ((const int4*)mask)[g];
    unsigned int s0 = (unsigned int)min(max(m.x, 0), NSEG - 1);
    unsigned int s1 = (unsigned int)min(max(m.y, 0), NSEG - 1);
    unsigned int s2 = (unsigned int)min(max(m.z, 0), NSEG - 1);
    unsigned int s3 = (unsigned int)min(max(m.w, 0), NSEG - 1);
    sb[g] = s0 | (s1 << 8) | (s2 << 16) | (s3 << 24);
}

// One block per patch cell; accumulate feature vector into transposed sums[b][c][s].
__global__ void accum_kernel(const float* __restrict__ F, const int* __restrict__ mask,
                             float* __restrict__ sums, float* __restrict__ counts) {
    int cell = blockIdx.x;                   // 0 .. BB*HP*WP-1
    int b = cell / (HP * WP);
    int rem = cell - b * (HP * WP);
    int hp = rem / WP;
    int wp = rem - hp * WP;
    // ih = hp*HI/HP = hp*14 exactly; iw = wp*14
    int m = mask[(size_t)b * NPIX + (hp * 14) * WI + (wp * 14)];
    int s = min(max(m, 0), NSEG - 1);
    for (int c = threadIdx.x; c < CC; c += blockDim.x) {
        float v = F[((b * CC + c) * HP + hp) * WP + wp];
        atomicAdd(&sums[(size_t)(b * CC + c) * NSEG + s], v);
    }
    if (threadIdx.x == 0) atomicAdd(&counts[b * NSEG + s], 1.0f);
}

// In-place: convert channel-pair (2*c2, 2*c2+1) sums into interleaved float2
// averages occupying the SAME 1 KB region. One block per (b, c2); read both
// channels into registers, sync, write back interleaved. No extra workspace.
__global__ __launch_bounds__(128) void div_kernel(float* __restrict__ sums,
                                                  const float* __restrict__ counts) {
    int pair = blockIdx.x;                   // 0 .. BB*CC2-1
    int b = pair / CC2;
    int s = threadIdx.x;                     // 0..127
    float* base = sums + ((size_t)pair << 8);        // pair*2*NSEG floats
    float cnt = counts[b * NSEG + s];
    float v0 = base[s];
    float v1 = base[s + NSEG];
    float inv = (cnt > 0.0f) ? (1.0f / cnt) : 0.0f;
    __syncthreads();
    ((float2*)base)[s] = make_float2(v0 * inv, v1 * inv);
}

// Paint: each thread owns 4 consecutive pixels; per iteration it serves 2 channels
// via float2 table gathers (halved gather-instruction count) and 2 nontemporal
// float4 stores. Per-block table slice = 32 KiB (L1-resident).
__global__ __launch_bounds__(256) void paint_kernel(const float2* __restrict__ avg2,
                                                    const unsigned int* __restrict__ sb,
                                                    float* __restrict__ out) {
    int b = blockIdx.z;
    int g = blockIdx.x * blockDim.x + threadIdx.x;   // float4 group within batch
    if (g >= NPIX4) return;
    unsigned int packed = sb[(size_t)b * NPIX4 + g];
    int s0 = packed & 255;
    int s1 = (packed >> 8) & 255;
    int s2 = (packed >> 16) & 255;
    int s3 = (packed >> 24) & 255;
    int p2 = blockIdx.y * CPB2;                      // channel-pair base
    const float2* tbl = avg2 + ((size_t)(b * CC2 + p2) << 7);
    f32x4* outp = (f32x4*)out + (size_t)(b * CC + 2 * p2) * NPIX4 + g;
    #pragma unroll 8
    for (int i = 0; i < CPB2; ++i) {
        const float2* t = tbl + ((size_t)i << 7);
        float2 a = t[s0], bb = t[s1], c = t[s2], d = t[s3];
        f32x4 lo = {a.x, bb.x, c.x, d.x};
        f32x4 hi = {a.y, bb.y, c.y, d.y};
        __builtin_nontemporal_store(lo, outp + (size_t)(2 * i) * NPIX4);
        __builtin_nontemporal_store(hi, outp + (size_t)(2 * i + 1) * NPIX4);
    }
}

extern "C" void kernel_launch(void* const* d_in, const int* in_sizes, int n_in,
                              void* d_out, int out_size, void* d_ws, size_t ws_size,
                              hipStream_t stream) {
    const float* F = (const float*)d_in[0];
    const int* mask = (const int*)d_in[1];
    float* out = (float*)d_out;

    float* sums = (float*)d_ws;                            // BB*CC*NSEG floats (786,432 B)
    float* counts = sums + BB * CC * NSEG;                 // BB*NSEG floats (1,024 B)
    unsigned int* sb = (unsigned int*)(counts + BB * NSEG);// BB*NPIX4 words (307,328 B)
    // Total workspace: 1,094,784 B — identical footprint to the verified baseline.

    // Zero sums + counts (ws is poisoned each call).
    (void)hipMemsetAsync(d_ws, 0, (size_t)(BB * CC * NSEG + BB * NSEG) * sizeof(float), stream);

    int ngroups = BB * NPIX4;                                   // 76,832
    pid_kernel<<<(ngroups + 255) / 256, 256, 0, stream>>>(mask, sb);
    accum_kernel<<<BB * HP * WP, 256, 0, stream>>>(F, mask, sums, counts);
    div_kernel<<<BB * CC2, 128, 0, stream>>>(sums, counts);
    paint_kernel<<<dim3((NPIX4 + 255) / 256, CC2 / CPB2, BB), 256, 0, stream>>>(
        (const float2*)sums, sb, out);
}